// Round 1
// baseline (425.107 us; speedup 1.0000x reference)
//
#include <hip/hip_runtime.h>

typedef _Float16 half_t;
typedef _Float16 half4 __attribute__((ext_vector_type(4)));
typedef float f32x4 __attribute__((ext_vector_type(4)));

static constexpr int NBATCH = 65536;

__device__ const int SEG_START[30] = {1,12,21,32,38,49,60,68,79,90,
  100,102,107,117,120,170,174,176,184,284,290,292,295,307,312,314,344,348,357,359};
__device__ const int SEG_LEN[30] = {10,8,10,5,10,10,7,10,10,10,
  2,5,10,3,50,4,2,8,100,6,2,3,12,5,2,30,4,9,2,7};
__device__ const int ALPHA_COL[10] = {0,11,20,31,37,48,59,67,78,89};

// ---------- f32 -> f16 convert (vector4) ----------
__global__ __launch_bounds__(256) void k_cvt(const float* __restrict__ x,
                                             half_t* __restrict__ y, int n4) {
  int i = blockIdx.x * 256 + threadIdx.x;
  if (i >= n4) return;
  float4 v = ((const float4*)x)[i];
  half4 h;
  h[0] = (half_t)v.x; h[1] = (half_t)v.y; h[2] = (half_t)v.z; h[3] = (half_t)v.w;
  ((half4*)y)[i] = h;
}

// ---------- W [K][N] f32 -> Wt [Npad][K] f16 (zero-pad n >= N) ----------
__global__ __launch_bounds__(256) void k_transpose(const float* __restrict__ W,
                                                   half_t* __restrict__ Wt,
                                                   int K, int N, int total) {
  int i = blockIdx.x * 256 + threadIdx.x;
  if (i >= total) return;
  int n = i / K;
  int k = i - n * K;
  float v = (n < N) ? W[k * N + n] : 0.f;
  Wt[i] = (half_t)v;
}

// ---------- GEMM: C[M][ldc] = concat(A0|A1|A2) [M][K] @ Bt^T, Bt is [N][K] f16 ----------
// 64x64 block tile, BK=32, 4 waves (2x2), each wave 32x32 via 2x2 mfma_f32_16x16x16f16
__global__ __launch_bounds__(256) void k_gemm(
    const half_t* __restrict__ A0, int w0,
    const half_t* __restrict__ A1, int w1,
    const half_t* __restrict__ A2, int w2,
    const half_t* __restrict__ Bt,
    const float* __restrict__ bias,
    float* __restrict__ C, int ldc, int ncols, int K) {
  __shared__ __align__(16) half_t As[64][40];  // 40-half stride: 80B, 16B-aligned rows
  __shared__ __align__(16) half_t Bs[64][40];  // Bs[n][k]
  const int tid  = threadIdx.x;
  const int lane = tid & 63;
  const int w    = tid >> 6;
  const int wr   = w >> 1, wc = w & 1;
  const int brow = blockIdx.y * 64;
  const int bcol = blockIdx.x * 64;
  const int r  = tid >> 2;         // 0..63 staging row
  const int c0 = (tid & 3) * 8;    // 0,8,16,24 staging col

  f32x4 acc[2][2];
#pragma unroll
  for (int i = 0; i < 2; i++)
#pragma unroll
    for (int j = 0; j < 2; j++) acc[i][j] = (f32x4){0.f, 0.f, 0.f, 0.f};

  const int w01 = w0 + w1;
  for (int k0 = 0; k0 < K; k0 += 32) {
    // A source select (tile K-ranges never straddle a source boundary: 256/512 % 32 == 0)
    int ka = k0 + c0;
    const half_t* ap; int aw, kk_;
    if (ka < w0)       { ap = A0; aw = w0; kk_ = ka; }
    else if (ka < w01) { ap = A1; aw = w1; kk_ = ka - w0; }
    else               { ap = A2; aw = w2; kk_ = ka - w01; }
    int4 av = *(const int4*)(ap + (size_t)(brow + r) * aw + kk_);
    int4 bv = *(const int4*)(Bt + (size_t)(bcol + r) * K + (k0 + c0));
    __syncthreads();
    *(int4*)&As[r][c0] = av;
    *(int4*)&Bs[r][c0] = bv;
    __syncthreads();
    const int g4 = (lane >> 4) * 4;
    const int ml = lane & 15;
#pragma unroll
    for (int kk = 0; kk < 32; kk += 16) {
      half4 a0 = *(const half4*)&As[wr * 32 + ml][kk + g4];
      half4 a1 = *(const half4*)&As[wr * 32 + 16 + ml][kk + g4];
      half4 b0 = *(const half4*)&Bs[wc * 32 + ml][kk + g4];
      half4 b1 = *(const half4*)&Bs[wc * 32 + 16 + ml][kk + g4];
      acc[0][0] = __builtin_amdgcn_mfma_f32_16x16x16f16(a0, b0, acc[0][0], 0, 0, 0);
      acc[0][1] = __builtin_amdgcn_mfma_f32_16x16x16f16(a0, b1, acc[0][1], 0, 0, 0);
      acc[1][0] = __builtin_amdgcn_mfma_f32_16x16x16f16(a1, b0, acc[1][0], 0, 0, 0);
      acc[1][1] = __builtin_amdgcn_mfma_f32_16x16x16f16(a1, b1, acc[1][1], 0, 0, 0);
    }
  }
  // C/D layout (m89-verified): col = lane&15, row = 4*(lane>>4)+reg
  const int colbase = bcol + wc * 32 + (lane & 15);
  const int rowbase = brow + wr * 32 + (lane >> 4) * 4;
#pragma unroll
  for (int fm = 0; fm < 2; fm++)
#pragma unroll
    for (int fn = 0; fn < 2; fn++) {
      int col = colbase + fn * 16;
      if (col < ncols) {
        float bz = bias[col];
#pragma unroll
        for (int rr = 0; rr < 4; rr++) {
          int row = rowbase + fm * 16 + rr;
          C[(size_t)row * ldc + col] = acc[fm][fn][rr] + bz;
        }
      }
    }
}

// ---------- column stats: partial sums over 128-row chunks ----------
__global__ __launch_bounds__(256) void k_stats_partial(const float* __restrict__ p,
                                                       float* __restrict__ ps,
                                                       float* __restrict__ pq) {
  int t = threadIdx.x, b = blockIdx.x;
  const float* base = p + (size_t)b * 128 * 256;
  float s0 = 0, s1 = 0, q0 = 0, q1 = 0;
#pragma unroll 4
  for (int r = 0; r < 128; r += 2) {
    float x0 = base[r * 256 + t];
    float x1 = base[(r + 1) * 256 + t];
    s0 += x0; q0 += x0 * x0;
    s1 += x1; q1 += x1 * x1;
  }
  ps[b * 256 + t] = s0 + s1;
  pq[b * 256 + t] = q0 + q1;
}

__global__ __launch_bounds__(256) void k_stats_final(const float* __restrict__ ps,
                                                     const float* __restrict__ pq,
                                                     const float* __restrict__ gamma,
                                                     const float* __restrict__ beta,
                                                     float* __restrict__ scale,
                                                     float* __restrict__ shift) {
  int t = threadIdx.x;
  float s = 0, q = 0;
  for (int b = 0; b < 512; b++) { s += ps[b * 256 + t]; q += pq[b * 256 + t]; }
  float mu   = s * (1.f / NBATCH);
  float var  = fmaxf(q * (1.f / NBATCH) - mu * mu, 0.f);
  float rstd = rsqrtf(var + 1e-3f);
  float sc   = gamma[t] * rstd;
  scale[t] = sc;
  shift[t] = beta[t] - mu * sc;
}

// ---------- apply BN+ReLU, emit f16 ----------
__global__ __launch_bounds__(256) void k_bn_relu(const float* __restrict__ p,
                                                 const float* __restrict__ scale,
                                                 const float* __restrict__ shift,
                                                 half_t* __restrict__ outh) {
  int i = blockIdx.x * 256 + threadIdx.x;  // over NBATCH*64 float4 groups
  float4 v = ((const float4*)p)[i];
  int c = (i & 63) * 4;
  half4 h;
  h[0] = (half_t)fmaxf(v.x * scale[c + 0] + shift[c + 0], 0.f);
  h[1] = (half_t)fmaxf(v.y * scale[c + 1] + shift[c + 1], 0.f);
  h[2] = (half_t)fmaxf(v.z * scale[c + 2] + shift[c + 2], 0.f);
  h[3] = (half_t)fmaxf(v.w * scale[c + 3] + shift[c + 3], 0.f);
  ((half4*)outh)[i] = h;
}

// ---------- in-place gumbel-softmax epilogue on logits in d_out ----------
__global__ __launch_bounds__(320) void k_epilogue(const float* __restrict__ g,
                                                  float* __restrict__ out) {
  __shared__ float zb[8][368];
  int row0 = blockIdx.x * 8;
  int tid  = threadIdx.x;
  for (int i = tid; i < 8 * 366; i += 320) {
    int r = i / 366, c = i - r * 366;
    size_t idx = (size_t)(row0 + r) * 366 + c;
    zb[r][c] = (out[idx] + g[idx]) * 5.0f;  // (logit+g)/TAU, TAU=0.2
  }
  __syncthreads();
  int r = tid / 40, t = tid - (tid / 40) * 40;  // 8 rows x 40 tasks
  if (t < 30) {
    int s = SEG_START[t], L = SEG_LEN[t];
    float m = -1e30f;
    for (int j = 0; j < L; j++) m = fmaxf(m, zb[r][s + j]);
    float sum = 0.f;
    for (int j = 0; j < L; j++) {
      float e = __expf(zb[r][s + j] - m);
      zb[r][s + j] = e;
      sum += e;
    }
    float inv = 1.0f / sum;
    size_t base = (size_t)(row0 + r) * 366;
    for (int j = 0; j < L; j++) out[base + s + j] = zb[r][s + j] * inv;
  } else {
    int c = ALPHA_COL[t - 30];
    size_t idx = (size_t)(row0 + r) * 366 + c;
    out[idx] = tanhf(out[idx]);  // raw logit still in d_out at this point
  }
}

extern "C" void kernel_launch(void* const* d_in, const int* in_sizes, int n_in,
                              void* d_out, int out_size, void* d_ws, size_t ws_size,
                              hipStream_t stream) {
  const float* z      = (const float*)d_in[0];
  const float* g      = (const float*)d_in[1];
  const float* W1     = (const float*)d_in[2];
  const float* b1     = (const float*)d_in[3];
  const float* gamma1 = (const float*)d_in[4];
  const float* beta1  = (const float*)d_in[5];
  const float* W2     = (const float*)d_in[6];
  const float* b2     = (const float*)d_in[7];
  const float* gamma2 = (const float*)d_in[8];
  const float* beta2  = (const float*)d_in[9];
  const float* Wout   = (const float*)d_in[10];
  const float* bout   = (const float*)d_in[11];
  float* out = (float*)d_out;
  char* ws = (char*)d_ws;

  size_t off = 0;
  half_t* zh  = (half_t*)(ws + off); off += (size_t)NBATCH * 128 * 2;  // 16 MB
  half_t* rb1 = (half_t*)(ws + off); off += (size_t)NBATCH * 256 * 2;  // 32 MB
  half_t* rb2 = (half_t*)(ws + off); off += (size_t)NBATCH * 256 * 2;  // 32 MB
  float*  p   = (float*)(ws + off);  off += (size_t)NBATCH * 256 * 4;  // 64 MB (reused for p1,p2)
  half_t* W1t = (half_t*)(ws + off); off += (size_t)256 * 128 * 2;
  half_t* W2t = (half_t*)(ws + off); off += (size_t)256 * 384 * 2;
  half_t* Wot = (half_t*)(ws + off); off += (size_t)384 * 640 * 2;
  float*  ps  = (float*)(ws + off);  off += (size_t)512 * 256 * 4;
  float*  pq  = (float*)(ws + off);  off += (size_t)512 * 256 * 4;
  float* scale1 = (float*)(ws + off); off += 1024;
  float* shift1 = (float*)(ws + off); off += 1024;
  float* scale2 = (float*)(ws + off); off += 1024;
  float* shift2 = (float*)(ws + off); off += 1024;
  (void)ws_size; (void)in_sizes; (void)n_in; (void)out_size;

  // prep: f16 z, transposed f16 weights
  k_cvt<<<8192, 256, 0, stream>>>(z, zh, NBATCH * 32);
  k_transpose<<<(256 * 128 + 255) / 256, 256, 0, stream>>>(W1, W1t, 128, 256, 256 * 128);
  k_transpose<<<(256 * 384 + 255) / 256, 256, 0, stream>>>(W2, W2t, 384, 256, 256 * 384);
  k_transpose<<<(384 * 640 + 255) / 256, 256, 0, stream>>>(Wout, Wot, 640, 366, 384 * 640);

  // layer 1: p1 = z @ W1 + b1 ; BN stats ; rb1 = f16(relu(bn(p1)))
  k_gemm<<<dim3(4, 1024), 256, 0, stream>>>(zh, 128, zh, 0, zh, 0, W1t, b1, p, 256, 256, 128);
  k_stats_partial<<<512, 256, 0, stream>>>(p, ps, pq);
  k_stats_final<<<1, 256, 0, stream>>>(ps, pq, gamma1, beta1, scale1, shift1);
  k_bn_relu<<<16384, 256, 0, stream>>>(p, scale1, shift1, rb1);

  // layer 2: p2 = [rb1|z] @ W2 + b2 ; BN stats ; rb2
  k_gemm<<<dim3(4, 1024), 256, 0, stream>>>(rb1, 256, zh, 128, zh, 0, W2t, b2, p, 256, 256, 384);
  k_stats_partial<<<512, 256, 0, stream>>>(p, ps, pq);
  k_stats_final<<<1, 256, 0, stream>>>(ps, pq, gamma2, beta2, scale2, shift2);
  k_bn_relu<<<16384, 256, 0, stream>>>(p, scale2, shift2, rb2);

  // output layer: logits = [rb2|rb1|z] @ Wout + bout -> d_out, then in-place gumbel-softmax
  k_gemm<<<dim3(6, 1024), 256, 0, stream>>>(rb2, 256, rb1, 256, zh, 128, Wot, bout, out, 366, 366, 640);
  k_epilogue<<<8192, 320, 0, stream>>>(g, out);
}